// Round 6
// baseline (41.774 us; speedup 1.0000x reference)
//
#include <hip/hip_runtime.h>
#include <stdint.h>

#define NE    7
#define DD    64
#define NDC   3
#define BLOCK 256
#define CHUNK 1792
#define NFRAG 18   // W^T A-fragments: 8 (L1) + 8 (L2) + 2 (L3)

typedef __fp16   half8 __attribute__((ext_vector_type(8)));
typedef float    f32x4 __attribute__((ext_vector_type(4)));
typedef uint32_t u32x4 __attribute__((ext_vector_type(4)));
typedef __fp16   h2_t  __attribute__((ext_vector_type(2)));

__device__ __forceinline__ uint32_t pkrtz(float a, float b) {
  h2_t h = __builtin_amdgcn_cvt_pkrtz(a, b);
  return __builtin_bit_cast(uint32_t, h);
}

// ---- pack W^T into A-fragment layout (layout HW-verified in R4) ----
__global__ void pack_w(const float* __restrict__ W1, const float* __restrict__ W2,
                       const float* __restrict__ W3, uint32_t* __restrict__ ws) {
  const int e = blockIdx.x;
  const float* Wl0 = W1 + e*DD*DD;
  const float* Wl1 = W2 + e*DD*DD;
  const float* Wl2 = W3 + e*DD*NDC;
  for (int idx = threadIdx.x; idx < NFRAG*64; idx += blockDim.x) {
    const int f = idx >> 6, l = idx & 63;
    int layer, fl;
    if (f < 8)       { layer = 0; fl = f; }
    else if (f < 16) { layer = 1; fl = f - 8; }
    else             { layer = 2; fl = f - 16; }
    const int nt = (layer < 2) ? (fl >> 1) : 0;
    const int ks = fl & 1;
    const int n  = nt*16 + (l & 15);
    const int g  = l >> 4;
    uint32_t dst[4];
    for (int d = 0; d < 4; ++d) {
      float v[2];
      for (int h = 0; h < 2; ++h) {
        const int kk = 16*(d>>1) + 4*g + 2*(d&1) + h;
        const int k  = 32*ks + kk;
        float val;
        if (layer == 0)      val = Wl0[k*DD + n];
        else if (layer == 1) val = Wl1[k*DD + n];
        else                 val = (n < NDC) ? Wl2[k*NDC + n] : 0.0f;
        v[h] = val;
      }
      dst[d] = pkrtz(v[0], v[1]);
    }
    uint32_t* p = ws + ((size_t)(e*NFRAG + f)*64 + l)*4;
    p[0]=dst[0]; p[1]=dst[1]; p[2]=dst[2]; p[3]=dst[3];
  }
}

__device__ __forceinline__ f32x4 mfma16(u32x4 a, u32x4 b, f32x4 c) {
  return __builtin_amdgcn_mfma_f32_16x16x32_f16(
      __builtin_bit_cast(half8, a), __builtin_bit_cast(half8, b), c, 0, 0, 0);
}

__device__ __forceinline__ u32x4 relu_pack(f32x4 lo, f32x4 hi) {
  u32x4 t = { pkrtz(fmaxf(lo[0],0.f), fmaxf(lo[1],0.f)),
              pkrtz(fmaxf(lo[2],0.f), fmaxf(lo[3],0.f)),
              pkrtz(fmaxf(hi[0],0.f), fmaxf(hi[1],0.f)),
              pkrtz(fmaxf(hi[2],0.f), fmaxf(hi[3],0.f)) };
  return t;
}

// issue gather for pass P into RJ/RAW (raw float4 regs stay live until consume)
#define LOADP(P, RJ, RAW) do {                                            \
  const int rel0_ = (P)*128 + wv*32;                                      \
  _Pragma("unroll")                                                       \
  for (int jt = 0; jt < 2; ++jt)                                          \
    RJ[jt] = list[min(rel0_ + jt*16 + r15, n-1)];                         \
  _Pragma("unroll")                                                       \
  for (int jt = 0; jt < 2; ++jt) {                                        \
    const float* xr_ = X + (size_t)RJ[jt]*DD;                             \
    _Pragma("unroll")                                                     \
    for (int ks = 0; ks < 2; ++ks) {                                      \
      RAW[jt][ks][0] = *(const float4*)(xr_ + 32*ks + 4*g);               \
      RAW[jt][ks][1] = *(const float4*)(xr_ + 32*ks + 16 + 4*g);          \
    }                                                                     \
  }                                                                       \
} while (0)

// consume RJ/RAW for pass P: pkrtz -> MFMA 3-layer pipeline -> softmax/store
#define COMPUTEP(P, RJ, RAW) do {                                         \
  const int rel0_ = (P)*128 + wv*32;                                      \
  u32x4 xf_[2][2];                                                        \
  _Pragma("unroll")                                                       \
  for (int jt = 0; jt < 2; ++jt) {                                        \
    _Pragma("unroll")                                                     \
    for (int ks = 0; ks < 2; ++ks) {                                      \
      const float4 v0_ = RAW[jt][ks][0], v1_ = RAW[jt][ks][1];            \
      u32x4 t_ = { pkrtz(v0_.x,v0_.y), pkrtz(v0_.z,v0_.w),                \
                   pkrtz(v1_.x,v1_.y), pkrtz(v1_.z,v1_.w) };              \
      xf_[jt][ks] = t_;                                                   \
    }                                                                     \
  }                                                                       \
  f32x4 c_[4][2];                                                         \
  _Pragma("unroll")                                                       \
  for (int nt = 0; nt < 4; ++nt) {                                        \
    const float4 bv_ = *(const float4*)(b1e + nt*16 + 4*g);               \
    _Pragma("unroll")                                                     \
    for (int jt = 0; jt < 2; ++jt) {                                      \
      f32x4 acc_ = { bv_.x, bv_.y, bv_.z, bv_.w };                        \
      acc_ = mfma16(af[nt*2+0], xf_[jt][0], acc_);                        \
      acc_ = mfma16(af[nt*2+1], xf_[jt][1], acc_);                        \
      c_[nt][jt] = acc_;                                                  \
    }                                                                     \
  }                                                                       \
  u32x4 hf_[2][2];                                                        \
  _Pragma("unroll")                                                       \
  for (int jt = 0; jt < 2; ++jt) {                                        \
    hf_[jt][0] = relu_pack(c_[0][jt], c_[1][jt]);                         \
    hf_[jt][1] = relu_pack(c_[2][jt], c_[3][jt]);                         \
  }                                                                       \
  _Pragma("unroll")                                                       \
  for (int nt = 0; nt < 4; ++nt) {                                        \
    const float4 bv_ = *(const float4*)(b2e + nt*16 + 4*g);               \
    _Pragma("unroll")                                                     \
    for (int jt = 0; jt < 2; ++jt) {                                      \
      f32x4 acc_ = { bv_.x, bv_.y, bv_.z, bv_.w };                        \
      acc_ = mfma16(af[8 + nt*2+0], hf_[jt][0], acc_);                    \
      acc_ = mfma16(af[8 + nt*2+1], hf_[jt][1], acc_);                    \
      c_[nt][jt] = acc_;                                                  \
    }                                                                     \
  }                                                                       \
  u32x4 h2f_[2][2];                                                       \
  _Pragma("unroll")                                                       \
  for (int jt = 0; jt < 2; ++jt) {                                        \
    h2f_[jt][0] = relu_pack(c_[0][jt], c_[1][jt]);                        \
    h2f_[jt][1] = relu_pack(c_[2][jt], c_[3][jt]);                        \
  }                                                                       \
  _Pragma("unroll")                                                       \
  for (int jt = 0; jt < 2; ++jt) {                                        \
    f32x4 acc_ = { bb0, bb1, bb2, 0.f };                                  \
    acc_ = mfma16(af[16], h2f_[jt][0], acc_);                             \
    acc_ = mfma16(af[17], h2f_[jt][1], acc_);                             \
    const int rel_ = rel0_ + jt*16 + r15;                                 \
    if (g == 0 && rel_ < n) {                                             \
      const int row_ = RJ[jt];                                            \
      const float l0_ = acc_[0], l1_ = acc_[1], l2_ = acc_[2];            \
      const float mx_  = fmaxf(l0_, fmaxf(l1_, l2_));                     \
      const float p0_  = __expf(l0_ - mx_);                               \
      const float p1_  = __expf(l1_ - mx_);                               \
      const float p2_  = __expf(l2_ - mx_);                               \
      const float inv_ = 1.0f / (p0_ + p1_ + p2_);                        \
      float* o_ = out + (size_t)row_*3;                                   \
      o_[0] = l0_; o_[1] = l1_; o_[2] = l2_;                              \
      float* pr_ = out + (size_t)B*3 + (size_t)row_*3;                    \
      pr_[0] = p0_*inv_; pr_[1] = p1_*inv_; pr_[2] = p2_*inv_;            \
    }                                                                     \
  }                                                                       \
} while (0)

__global__ __launch_bounds__(BLOCK) void moe_mfma(
    const float* __restrict__ X, const int* __restrict__ S,
    const uint32_t* __restrict__ ws,
    const float* __restrict__ b1, const float* __restrict__ b2,
    const float* __restrict__ b3,
    float* __restrict__ out, int B)
{
  __shared__ int list[CHUNK];
  __shared__ int cnt;

  const int e = blockIdx.y, tid = threadIdx.x;
  const int wv = tid >> 6, lane = tid & 63;
  const int r15 = lane & 15, g = lane >> 4;
  const int base = blockIdx.x * CHUNK;

  if (tid == 0) cnt = 0;
  __syncthreads();
  const int lim = min(CHUNK, B - base);
  for (int i = tid; i < lim; i += BLOCK) {
    const int row = base + i;
    const bool pred = (S[row] == e);
    const unsigned long long mask = __ballot(pred);
    const int prefix = __popcll(mask & ((1ull << lane) - 1ull));
    int bp = 0;
    if (lane == 0 && mask) bp = atomicAdd(&cnt, __popcll(mask));
    bp = __shfl(bp, 0, 64);
    if (pred) list[bp + prefix] = row;
  }
  __syncthreads();
  const int n = cnt;
  if (n == 0) return;

  // resident W^T fragments (72 VGPRs)
  const u32x4* wse = (const u32x4*)ws + (size_t)e*NFRAG*64;
  u32x4 af[NFRAG];
  #pragma unroll
  for (int f = 0; f < NFRAG; ++f) af[f] = wse[f*64 + lane];

  const float* b1e = b1 + e*DD;
  const float* b2e = b2 + e*DD;
  const float bb0 = b3[e*NDC+0], bb1 = b3[e*NDC+1], bb2 = b3[e*NDC+2];

  const int npass = (n + 127) >> 7;

  float4 rawA[2][2][2], rawB[2][2][2];
  int rjA[2], rjB[2];

  LOADP(0, rjA, rawA);
  int p = 0;
  while (true) {
    if (p + 1 < npass) LOADP(p + 1, rjB, rawB);
    COMPUTEP(p, rjA, rawA);
    ++p; if (p >= npass) break;
    if (p + 1 < npass) LOADP(p + 1, rjA, rawA);
    COMPUTEP(p, rjB, rawB);
    ++p; if (p >= npass) break;
  }
}

extern "C" void kernel_launch(void* const* d_in, const int* in_sizes, int n_in,
                              void* d_out, int out_size, void* d_ws, size_t ws_size,
                              hipStream_t stream)
{
  const float* X  = (const float*)d_in[0];
  const int*   S  = (const int*)d_in[1];
  const float* W1 = (const float*)d_in[2];
  const float* B1 = (const float*)d_in[3];
  const float* W2 = (const float*)d_in[4];
  const float* B2 = (const float*)d_in[5];
  const float* W3 = (const float*)d_in[6];
  const float* B3 = (const float*)d_in[7];
  float* out = (float*)d_out;
  uint32_t* ws = (uint32_t*)d_ws;

  const int B = in_sizes[0] / DD;   // 262144

  pack_w<<<NE, 256, 0, stream>>>(W1, W2, W3, ws);

  dim3 grid((B + CHUNK - 1) / CHUNK, NE);
  moe_mfma<<<grid, dim3(BLOCK), 0, stream>>>(X, S, ws, B1, B2, B3, out, B);
}